// Round 3
// baseline (383.143 us; speedup 1.0000x reference)
//
#include <hip/hip_runtime.h>

// ConvMlp4d: conv4d(64->128) + bias + relu -> conv4d(128->64) + bias.
// R13 = R12 counted-vmcnt pipeline + T5 setprio + depth-2 A prefetch.
//   - raw s_barrier + asm vmcnt(18): DMA(i) retired, B(i) refills may fly
//   - all B loads for unit i issued in iter i-1 AFTER DMA(i): consuming them
//     never force-drains DMA(i+1) (in-order vmcnt retirement)
//   - DMA unconditional (fixed count=7): halo lanes read a zero page; LDS
//     buffers padded to 896 slots so overflow lanes land in never-read pad
//   - s_setprio(1) around each 12-MFMA cluster (T5: counted-vmcnt structure
//     gives waves role-split -> scheduler favors MFMA-ready wave)
//   - A fragments prefetched 2 groups ahead (afA/afB/afC rotation): ds_read
//     latency (~120cy + contention) fully covered by ~2 MFMA clusters
//   - both convs: 128-thr blocks, 2 waves, wave tile M=128 (rr=4) x N=32,
//     VSPAN=4, ROWS=6; conv1 grid 2048 (COUT split 2), conv2 grid 1024
//   ws: x_t bf16 [2][65536][64] | h_t bf16 [2][65536][128] (chunk-planar:
//       [nb][tu][v][chunk=c/8][w][c%8])
//       w1t bf16 [81][4][128][16] | w2t bf16 [81][8][64][16] | zpage 4KB

using bf16x8 = __attribute__((ext_vector_type(8))) __bf16;
using f32x16 = __attribute__((ext_vector_type(16))) float;
using f32x4  = __attribute__((ext_vector_type(4))) float;

typedef __attribute__((address_space(1))) const void as1_void;
typedef __attribute__((address_space(3))) void as3_void;
__device__ __forceinline__ void gload_lds16(const void* g, void* l) {
    __builtin_amdgcn_global_load_lds((as1_void*)g, (as3_void*)l, 16, 0, 0);
}

// ------- prep: x (2,64,65536) f32 -> x_t chunk-planar bf16; zero the zpage --------
__global__ __launch_bounds__(256) void cvt_x(const float* __restrict__ x,
                                             __bf16* __restrict__ x_t,
                                             __bf16* __restrict__ zp) {
    __shared__ float lt[64][65];
    if (blockIdx.x == 0 && blockIdx.y == 0)
        *(uint4*)((char*)zp + threadIdx.x * 16) = make_uint4(0u, 0u, 0u, 0u);
    const int nb = blockIdx.y;
    const int p0 = blockIdx.x * 64;
    const int tu = p0 >> 10;
    const float* src = x + (size_t)nb * 64 * 65536;
    __bf16* dst = x_t + (size_t)nb * 65536 * 64;
    #pragma unroll
    for (int i = 0; i < 16; ++i) {
        int idx = i * 256 + threadIdx.x;
        int c = idx >> 6, p = idx & 63;
        lt[c][p] = src[(size_t)c * 65536 + p0 + p];
    }
    __syncthreads();
    #pragma unroll
    for (int it = 0; it < 2; ++it) {
        int idx = it * 256 + threadIdx.x;
        int pl = idx & 63;
        int chunk = idx >> 6;
        int p = p0 + pl;
        int v = (p >> 5) & 31, w = p & 31;
        bf16x8 pk;
        #pragma unroll
        for (int e = 0; e < 8; ++e)
            pk[e] = (__bf16)lt[chunk * 8 + e][pl];
        *(bf16x8*)(dst + (size_t)(tu * 32 + v) * 2048 + chunk * 256 + w * 8) = pk;
    }
}

// ------- prep: w (O,CIN,81) f32 -> wt [81][CIN/16][COUT][16] bf16 ------------------
template <int CIN>
__global__ __launch_bounds__(256) void cvt_w(const float* __restrict__ w,
                                             __bf16* __restrict__ wt) {
    constexpr int COUT = 8192 / CIN;
    constexpr int LOGC = (CIN == 64) ? 7 : 6;   // log2(COUT)
    const int tap = blockIdx.x;                 // 0..80
    __bf16* dst = wt + (size_t)tap * 8192;
    #pragma unroll
    for (int it = 0; it < 32; ++it) {
        const int i  = it * 256 + threadIdx.x;  // kg*(COUT*16) + o*16 + cl
        const int cl = i & 15;
        const int o  = (i >> 4) & (COUT - 1);
        const int kg = i >> (4 + LOGC);
        dst[i] = (__bf16)w[(size_t)(o * CIN + kg * 16 + cl) * 81 + tap];
    }
}

// ---------------- fused conv4d (implicit GEMM, 32x32x16 bf16 MFMA) -----------------
// Block 128 thr = 2 waves (gni = wave). Wave tile M=128 (rr=4), N=32.
// Block tile M=128 (v-span 4), N=64; conv1 splits COUT 128 into 2 n-blocks.
// Staging unit = one (kt,ku) stage x 32 channels: LDS [6 rows][chunk4][wp34] 16B
// slots, padded to 896/buffer; ping-pong. Counted-vmcnt pipeline (see header).
template <int CIN, int COUT, int NSPLIT, bool RELU>
__global__ __launch_bounds__(128, 2) void conv4d_mfma(
    const __bf16* __restrict__ in_t,   // chunk-planar activations
    const __bf16* __restrict__ wt,     // [81][CIN/16][COUT][16]
    const float* __restrict__ bias,    // [COUT]
    __bf16* __restrict__ out_bf,       // chunk-planar (RELU path)
    float* __restrict__ out_f,         // [2][COUT][65536]  (else)
    const __bf16* __restrict__ zpage)  // 4KB of zeros
{
    constexpr int KST     = CIN / 16;
    constexpr int UNITS   = CIN / 32;
    constexpr int LOGU    = (UNITS == 2) ? 1 : 2;
    constexpr int SLOTS   = 6 * 136;               // 816 valid 16B slots
    constexpr int SLOTS_P = 896;                   // padded to 7*128
    constexpr int RNDS    = 7;                     // DMA rounds (128 thr each)
    constexpr int BUFB_P  = SLOTS_P * 16;          // 14336 B

    __shared__ __bf16 tile[2 * SLOTS_P * 8];       // ping-pong, 28672 B

    const int tid  = threadIdx.x;                  // 0..127
    const int lane = tid & 63;
    const int l31  = lane & 31;
    const int hl   = lane >> 5;
    const int wv   = tid >> 6;                     // 0..1 = gni

    // grid: xcd(3) | ulo(1) | vg(3) | t(2) | nb(1) | nsp(log2 NSPLIT)
    const int bid = blockIdx.x;
    const int xcd = bid & 7;
    const int s0  = bid >> 3;
    const int u   = xcd * 2 + (s0 & 1);
    const int vg  = (s0 >> 1) & 7;
    const int t   = (s0 >> 4) & 3;
    const int nb  = (s0 >> 6) & 1;
    const int nsp = (s0 >> 7) & (NSPLIT - 1);
    const int v0  = vg * 4;
    const int pbase = ((t * 16 + u) * 32 + v0) * 32;

    const __bf16* inb = in_t + (size_t)nb * 65536 * CIN;

    // ---- per-lane staging offsets (slot = r*128 + tid), chunk-planar global ----
    int goff[RNDS];
    #pragma unroll
    for (int r = 0; r < RNDS; ++r) {
        const int slot = r * 128 + tid;            // 16B-chunk slot
        const int row  = slot / 136;               // LDS [6][chunk4][wp34]
        const int rem  = slot - row * 136;
        const int chunk = rem / 34;
        const int wp   = rem - chunk * 34;
        const int v_in = v0 - 1 + row;
        const int w_in = wp - 1;
        const bool ok = (slot < SLOTS) && ((unsigned)v_in < 32u) &&
                        ((unsigned)w_in < 32u);
        goff[r] = ok ? (v_in * (CIN * 32) + chunk * 256 + w_in * 8) : -1;
    }

    // A-read lane base (16B slots): slot = j*136 + (ks*2+hl)*34 + l31 + kw
    const int lane_base = hl * 34 + l31;
    const bf16x8* tile16 = (const bf16x8*)tile;

    // B lane pointer: o = nsp*64 + gni*32 + l31; + hl*8 within the 16-ch group
    const int o = nsp * 64 + wv * 32 + l31;
    const __bf16* wlane = wt + (size_t)o * 16 + hl * 8;

    // ---- valid (kt,ku) stage list (block-uniform) ----
    int sb[9], tb0[9], nst = 0;
    #pragma unroll
    for (int kt = 0; kt < 3; ++kt) {
        const int t_in = t + kt - 1;
        if ((unsigned)t_in >= 4u) continue;
        #pragma unroll
        for (int ku = 0; ku < 3; ++ku) {
            const int u_in = u + ku - 1;
            if ((unsigned)u_in >= 16u) continue;
            sb[nst]  = (t_in * 16 + u_in) * 1024 * CIN;
            tb0[nst] = (kt * 3 + ku) * 9;
            ++nst;
        }
    }
    const int U = nst * UNITS;

    f32x16 acc[4];
    #pragma unroll
    for (int mt = 0; mt < 4; ++mt)
        #pragma unroll
        for (int i = 0; i < 16; ++i)
            acc[mt][i] = 0.f;

    // DMA issue for unit j into buffer `buf` (UNCONDITIONAL: 7 insts/wave;
    // halo/pad lanes read the zero page)
    auto issue = [&](int buf, int j) {
        const int st = j >> LOGU, ch = j & (UNITS - 1);
        const __bf16* gb = inb + sb[st] + ch * 1024;   // unit = 4 chunk-planes
        char* lb = ((char*)tile) + buf * BUFB_P + wv * 1024;
        #pragma unroll
        for (int r = 0; r < RNDS; ++r) {
            const __bf16* ga = (goff[r] >= 0) ? gb + goff[r] : zpage;
            gload_lds16(ga, lb + r * 2048);
        }
    };

    // A-fragment group load (6x ds_read_b128); g = (ks*3 + kw)
    auto ldA = [&](const bf16x8* tb, int g, bf16x8 (&af)[6]) {
        const int ks = g / 3, kw = g % 3;
        #pragma unroll
        for (int j = 0; j < 6; ++j)
            af[j] = tb[j * 136 + ks * 68 + kw];
    };
    // B-fragment group load (3x global 16B, L2-resident weights)
    auto ldB = [&](int tapb, int ch, int g, bf16x8 (&bv)[3]) {
        const int ks = g / 3, kw = g % 3;
        const int ksg = ch * 2 + ks;
        #pragma unroll
        for (int kv = 0; kv < 3; ++kv) {
            const int wo = ((tapb + kv * 3 + kw) * KST + ksg) * (COUT * 16);
            bv[kv] = *(const bf16x8*)(wlane + wo);
        }
    };
    // one (ks,kw) group's MFMA cluster (T5: boost wave priority while issuing)
    auto mfma12 = [&](bf16x8 (&af)[6], bf16x8 (&bv)[3]) {
        __builtin_amdgcn_s_setprio(1);
        #pragma unroll
        for (int kv = 0; kv < 3; ++kv)
            #pragma unroll
            for (int rr = 0; rr < 4; ++rr)
                acc[rr] = __builtin_amdgcn_mfma_f32_32x32x16_bf16(
                    af[rr + kv], bv[kv], acc[rr], 0, 0, 0);
        __builtin_amdgcn_s_setprio(0);
    };

    // ---- prologue: DMA(0) then B(0) (B younger than DMA(0) -> vmcnt(18) ok) ----
    issue(0, 0);
    bf16x8 bv[6][3];
    #pragma unroll
    for (int g = 0; g < 6; ++g)
        ldB(tb0[0], 0, g, bv[g]);

    #pragma unroll 1
    for (int i = 0; i < U; ++i) {
        // Outstanding here: DMA(i) [7, oldest] + B(i) refills [18, youngest].
        // vmcnt(18) retires exactly DMA(i); B(i) may still be in flight.
        asm volatile("s_waitcnt vmcnt(18)" ::: "memory");
        __builtin_amdgcn_s_barrier();
        __builtin_amdgcn_sched_barrier(0);

        const bool more = (i + 1 < U);
        const int nu = more ? i + 1 : i;          // last iter: dummy (discarded)
        issue((i + 1) & 1, nu);                   // DMA(i+1): full-unit cover
        __builtin_amdgcn_sched_barrier(0);

        const int ntapb = tb0[nu >> LOGU];
        const int nch   = nu & (UNITS - 1);
        const bf16x8* tb = tile16 + (i & 1) * SLOTS_P + lane_base;

        // depth-2 A rotation: ldA(g+2) issued during cluster g
        bf16x8 afA[6], afB[6], afC[6];
        ldA(tb, 0, afA);
        ldA(tb, 1, afB);
        ldA(tb, 2, afC);                          // g0..g2 in flight
        mfma12(afA, bv[0]); ldA(tb, 3, afA); ldB(ntapb, nch, 0, bv[0]);
        mfma12(afB, bv[1]); ldA(tb, 4, afB); ldB(ntapb, nch, 1, bv[1]);
        mfma12(afC, bv[2]); ldA(tb, 5, afC); ldB(ntapb, nch, 2, bv[2]);
        mfma12(afA, bv[3]); ldB(ntapb, nch, 3, bv[3]);
        mfma12(afB, bv[4]); ldB(ntapb, nch, 4, bv[4]);
        mfma12(afC, bv[5]); ldB(ntapb, nch, 5, bv[5]);
    }

    // ---- epilogue: C/D 32x32: col = lane&31, row = (reg&3) + 8*(reg>>2) + 4*hl ----
    {
        const float bvls = bias[o];
        #pragma unroll
        for (int rr = 0; rr < 4; ++rr) {
            const int pb = pbase + rr * 32;
            if constexpr (RELU) {
                #pragma unroll
                for (int rg = 0; rg < 4; ++rg)
                    #pragma unroll
                    for (int j = 0; j < 4; ++j) {
                        float v = acc[rr][rg * 4 + j] + bvls;
                        v = v > 0.f ? v : 0.f;
                        const int p = pb + j + 8 * rg + 4 * hl;
                        const int vv = (p >> 5) & 31, ww = p & 31, tu = p >> 10;
                        out_bf[(size_t)nb * 65536 * COUT +
                               (size_t)(tu * 32 + vv) * (32 * COUT) +
                               (o >> 3) * 256 + ww * 8 + (o & 7)] = (__bf16)v;
                    }
            } else {
                #pragma unroll
                for (int rg = 0; rg < 4; ++rg) {
                    f32x4 sv;
                    #pragma unroll
                    for (int j = 0; j < 4; ++j)
                        sv[j] = acc[rr][rg * 4 + j] + bvls;
                    const int p = pb + 8 * rg + 4 * hl;
                    *(f32x4*)(out_f + ((size_t)nb * COUT + o) * 65536 + p) = sv;
                }
            }
        }
    }
}

extern "C" void kernel_launch(void* const* d_in, const int* in_sizes, int n_in,
                              void* d_out, int out_size, void* d_ws, size_t ws_size,
                              hipStream_t stream) {
    const float* x  = (const float*)d_in[0];
    const float* w1 = (const float*)d_in[1];
    const float* b1 = (const float*)d_in[2];
    const float* w2 = (const float*)d_in[3];
    const float* b2 = (const float*)d_in[4];
    float* out = (float*)d_out;

    char* ws = (char*)d_ws;
    __bf16* x_t = (__bf16*)ws;                               // 16,777,216 B
    __bf16* h_t = (__bf16*)(ws + 16777216);                  // 33,554,432 B
    __bf16* w1t = (__bf16*)(ws + 50331648);                  //  1,327,104 B
    __bf16* w2t = (__bf16*)(ws + 51658752);                  //  1,327,104 B
    __bf16* zpg = (__bf16*)(ws + 52985856);                  //      4,096 B

    cvt_x<<<dim3(1024, 2), 256, 0, stream>>>(x, x_t, zpg);
    cvt_w<64><<<81, 256, 0, stream>>>(w1, w1t);
    cvt_w<128><<<81, 256, 0, stream>>>(w2, w2t);

    // conv1: 128-thr blocks, M=128 N=64, COUT split 2 -> grid 2048
    conv4d_mfma<64, 128, 2, true><<<2048, 128, 0, stream>>>(x_t, w1t, b1, h_t,
                                                            nullptr, zpg);
    // conv2: 128-thr blocks, M=128 N=64, grid 1024 (4 blocks/CU)
    conv4d_mfma<128, 64, 1, false><<<1024, 128, 0, stream>>>(h_t, w2t, b2,
                                                             nullptr, out, zpg);
}

// Round 4
// 374.068 us; speedup vs baseline: 1.0243x; 1.0243x over previous
//
#include <hip/hip_runtime.h>

// ConvMlp4d: conv4d(64->128) + bias + relu -> conv4d(128->64) + bias.
// R14 = R12 geometry, but waitcnt-robust schedule: no vmem value lives
// across the loop back-edge or the inline-asm wait, so the compiler can
// insert minimal intra-body waitcnts (the R12/R13 back-edge bv[] forced
// conservative vmcnt waits before every MFMA cluster -> ~25% wave duty).
//   per iteration: [vmcnt(0)+barrier (DMA(i) had full-unit cover)]
//                  [ldB x18 for unit i]  <- L2, ~300cy, only g0 partially waits
//                  [issue DMA(i+1)]      <- younger than all B: consuming B
//                                           never forces DMA retirement
//                  [6 clusters: ldA(g+1) || 12 MFMA(g)]
//   - DMA unconditional (7 insts): halo lanes read a zero page; LDS padded
//     to 896 slots/buffer so overflow lanes land in never-read pad
//   - both convs: 128-thr blocks, 2 waves, wave tile M=128 (rr=4) x N=32,
//     VSPAN=4, ROWS=6; conv1 grid 2048 (COUT split 2), conv2 grid 1024
//   ws: x_t bf16 [2][65536][64] | h_t bf16 [2][65536][128] (chunk-planar:
//       [nb][tu][v][chunk=c/8][w][c%8])
//       w1t bf16 [81][4][128][16] | w2t bf16 [81][8][64][16] | zpage 4KB

using bf16x8 = __attribute__((ext_vector_type(8))) __bf16;
using f32x16 = __attribute__((ext_vector_type(16))) float;
using f32x4  = __attribute__((ext_vector_type(4))) float;

typedef __attribute__((address_space(1))) const void as1_void;
typedef __attribute__((address_space(3))) void as3_void;
__device__ __forceinline__ void gload_lds16(const void* g, void* l) {
    __builtin_amdgcn_global_load_lds((as1_void*)g, (as3_void*)l, 16, 0, 0);
}

// ------- prep: x (2,64,65536) f32 -> x_t chunk-planar bf16; zero the zpage --------
__global__ __launch_bounds__(256) void cvt_x(const float* __restrict__ x,
                                             __bf16* __restrict__ x_t,
                                             __bf16* __restrict__ zp) {
    __shared__ float lt[64][65];
    if (blockIdx.x == 0 && blockIdx.y == 0)
        *(uint4*)((char*)zp + threadIdx.x * 16) = make_uint4(0u, 0u, 0u, 0u);
    const int nb = blockIdx.y;
    const int p0 = blockIdx.x * 64;
    const int tu = p0 >> 10;
    const float* src = x + (size_t)nb * 64 * 65536;
    __bf16* dst = x_t + (size_t)nb * 65536 * 64;
    #pragma unroll
    for (int i = 0; i < 16; ++i) {
        int idx = i * 256 + threadIdx.x;
        int c = idx >> 6, p = idx & 63;
        lt[c][p] = src[(size_t)c * 65536 + p0 + p];
    }
    __syncthreads();
    #pragma unroll
    for (int it = 0; it < 2; ++it) {
        int idx = it * 256 + threadIdx.x;
        int pl = idx & 63;
        int chunk = idx >> 6;
        int p = p0 + pl;
        int v = (p >> 5) & 31, w = p & 31;
        bf16x8 pk;
        #pragma unroll
        for (int e = 0; e < 8; ++e)
            pk[e] = (__bf16)lt[chunk * 8 + e][pl];
        *(bf16x8*)(dst + (size_t)(tu * 32 + v) * 2048 + chunk * 256 + w * 8) = pk;
    }
}

// ------- prep: w (O,CIN,81) f32 -> wt [81][CIN/16][COUT][16] bf16 ------------------
template <int CIN>
__global__ __launch_bounds__(256) void cvt_w(const float* __restrict__ w,
                                             __bf16* __restrict__ wt) {
    constexpr int COUT = 8192 / CIN;
    constexpr int LOGC = (CIN == 64) ? 7 : 6;   // log2(COUT)
    const int tap = blockIdx.x;                 // 0..80
    __bf16* dst = wt + (size_t)tap * 8192;
    #pragma unroll
    for (int it = 0; it < 32; ++it) {
        const int i  = it * 256 + threadIdx.x;  // kg*(COUT*16) + o*16 + cl
        const int cl = i & 15;
        const int o  = (i >> 4) & (COUT - 1);
        const int kg = i >> (4 + LOGC);
        dst[i] = (__bf16)w[(size_t)(o * CIN + kg * 16 + cl) * 81 + tap];
    }
}

// ---------------- fused conv4d (implicit GEMM, 32x32x16 bf16 MFMA) -----------------
// Block 128 thr = 2 waves (gni = wave). Wave tile M=128 (rr=4), N=32.
// Block tile M=128 (v-span 4), N=64; conv1 splits COUT 128 into 2 n-blocks.
// Staging unit = one (kt,ku) stage x 32 channels: LDS [6 rows][chunk4][wp34] 16B
// slots, padded to 896/buffer; ping-pong.
template <int CIN, int COUT, int NSPLIT, bool RELU>
__global__ __launch_bounds__(128, 2) void conv4d_mfma(
    const __bf16* __restrict__ in_t,   // chunk-planar activations
    const __bf16* __restrict__ wt,     // [81][CIN/16][COUT][16]
    const float* __restrict__ bias,    // [COUT]
    __bf16* __restrict__ out_bf,       // chunk-planar (RELU path)
    float* __restrict__ out_f,         // [2][COUT][65536]  (else)
    const __bf16* __restrict__ zpage)  // 4KB of zeros
{
    constexpr int KST     = CIN / 16;
    constexpr int UNITS   = CIN / 32;
    constexpr int LOGU    = (UNITS == 2) ? 1 : 2;
    constexpr int SLOTS   = 6 * 136;               // 816 valid 16B slots
    constexpr int SLOTS_P = 896;                   // padded to 7*128
    constexpr int RNDS    = 7;                     // DMA rounds (128 thr each)
    constexpr int BUFB_P  = SLOTS_P * 16;          // 14336 B

    __shared__ __bf16 tile[2 * SLOTS_P * 8];       // ping-pong, 28672 B

    const int tid  = threadIdx.x;                  // 0..127
    const int lane = tid & 63;
    const int l31  = lane & 31;
    const int hl   = lane >> 5;
    const int wv   = tid >> 6;                     // 0..1 = gni

    // grid: xcd(3) | ulo(1) | vg(3) | t(2) | nb(1) | nsp(log2 NSPLIT)
    const int bid = blockIdx.x;
    const int xcd = bid & 7;
    const int s0  = bid >> 3;
    const int u   = xcd * 2 + (s0 & 1);
    const int vg  = (s0 >> 1) & 7;
    const int t   = (s0 >> 4) & 3;
    const int nb  = (s0 >> 6) & 1;
    const int nsp = (s0 >> 7) & (NSPLIT - 1);
    const int v0  = vg * 4;
    const int pbase = ((t * 16 + u) * 32 + v0) * 32;

    const __bf16* inb = in_t + (size_t)nb * 65536 * CIN;

    // ---- per-lane staging offsets (slot = r*128 + tid), chunk-planar global ----
    int goff[RNDS];
    #pragma unroll
    for (int r = 0; r < RNDS; ++r) {
        const int slot = r * 128 + tid;            // 16B-chunk slot
        const int row  = slot / 136;               // LDS [6][chunk4][wp34]
        const int rem  = slot - row * 136;
        const int chunk = rem / 34;
        const int wp   = rem - chunk * 34;
        const int v_in = v0 - 1 + row;
        const int w_in = wp - 1;
        const bool ok = (slot < SLOTS) && ((unsigned)v_in < 32u) &&
                        ((unsigned)w_in < 32u);
        goff[r] = ok ? (v_in * (CIN * 32) + chunk * 256 + w_in * 8) : -1;
    }

    // A-read lane base (16B slots): slot = j*136 + (ks*2+hl)*34 + l31 + kw
    const int lane_base = hl * 34 + l31;
    const bf16x8* tile16 = (const bf16x8*)tile;

    // B lane pointer: o = nsp*64 + gni*32 + l31; + hl*8 within the 16-ch group
    const int o = nsp * 64 + wv * 32 + l31;
    const __bf16* wlane = wt + (size_t)o * 16 + hl * 8;

    // ---- valid (kt,ku) stage list (block-uniform) ----
    int sb[9], tb0[9], nst = 0;
    #pragma unroll
    for (int kt = 0; kt < 3; ++kt) {
        const int t_in = t + kt - 1;
        if ((unsigned)t_in >= 4u) continue;
        #pragma unroll
        for (int ku = 0; ku < 3; ++ku) {
            const int u_in = u + ku - 1;
            if ((unsigned)u_in >= 16u) continue;
            sb[nst]  = (t_in * 16 + u_in) * 1024 * CIN;
            tb0[nst] = (kt * 3 + ku) * 9;
            ++nst;
        }
    }
    const int U = nst * UNITS;

    f32x16 acc[4];
    #pragma unroll
    for (int mt = 0; mt < 4; ++mt)
        #pragma unroll
        for (int i = 0; i < 16; ++i)
            acc[mt][i] = 0.f;

    // DMA issue for unit j into buffer `buf` (UNCONDITIONAL: 7 insts/wave;
    // halo/pad lanes read the zero page)
    auto issue = [&](int buf, int j) {
        const int st = j >> LOGU, ch = j & (UNITS - 1);
        const __bf16* gb = inb + sb[st] + ch * 1024;   // unit = 4 chunk-planes
        char* lb = ((char*)tile) + buf * BUFB_P + wv * 1024;
        #pragma unroll
        for (int r = 0; r < RNDS; ++r) {
            const __bf16* ga = (goff[r] >= 0) ? gb + goff[r] : zpage;
            gload_lds16(ga, lb + r * 2048);
        }
    };

    // A-fragment group load (6x ds_read_b128); g = (ks*3 + kw)
    auto ldA = [&](const bf16x8* tb, int g, bf16x8 (&af)[6]) {
        const int ks = g / 3, kw = g % 3;
        #pragma unroll
        for (int j = 0; j < 6; ++j)
            af[j] = tb[j * 136 + ks * 68 + kw];
    };
    // B-fragment group load (3x global 16B, L2-resident weights)
    auto ldB = [&](int tapb, int ch, int g, bf16x8 (&bv)[3]) {
        const int ks = g / 3, kw = g % 3;
        const int ksg = ch * 2 + ks;
        #pragma unroll
        for (int kv = 0; kv < 3; ++kv) {
            const int wo = ((tapb + kv * 3 + kw) * KST + ksg) * (COUT * 16);
            bv[kv] = *(const bf16x8*)(wlane + wo);
        }
    };
    // one (ks,kw) group's MFMA cluster
    auto mfma12 = [&](bf16x8 (&af)[6], bf16x8 (&bv)[3]) {
        #pragma unroll
        for (int kv = 0; kv < 3; ++kv)
            #pragma unroll
            for (int rr = 0; rr < 4; ++rr)
                acc[rr] = __builtin_amdgcn_mfma_f32_32x32x16_bf16(
                    af[rr + kv], bv[kv], acc[rr], 0, 0, 0);
    };

    issue(0, 0);

    #pragma unroll 1
    for (int i = 0; i < U; ++i) {
        // DMA(i) was issued a full unit ago (or in the prologue): cheap wait.
        // Nothing vmem-valued is live across this point -> compiler's
        // intra-body waitcnt tracking starts clean each iteration.
        asm volatile("s_waitcnt vmcnt(0)" ::: "memory");
        __builtin_amdgcn_s_barrier();

        const int st = i >> LOGU, ch = i & (UNITS - 1);
        const int tapb = tb0[st];
        const bf16x8* tb = tile16 + (i & 1) * SLOTS_P + lane_base;

        // B for THIS unit, loaded up front (L2-resident; g0 waits ~200cy,
        // later groups fully covered by earlier clusters)
        bf16x8 bvv[6][3];
        #pragma unroll
        for (int g = 0; g < 6; ++g)
            ldB(tapb, ch, g, bvv[g]);
        __builtin_amdgcn_sched_barrier(0);
        // DMA(i+1) AFTER all B loads: it is younger than every vmem value
        // consumed this iteration, so no bv-consumer wait retires it.
        if (i + 1 < U) issue((i + 1) & 1, i + 1);
        __builtin_amdgcn_sched_barrier(0);

        bf16x8 afA[6], afB[6];
        // groups g=(ks,kw): g0=(0,0) g1=(0,1) g2=(0,2) g3=(1,0) g4=(1,1) g5=(1,2)
        ldA(tb, 0, afA);
        ldA(tb, 1, afB);
        mfma12(afA, bvv[0]);
        ldA(tb, 2, afA);
        mfma12(afB, bvv[1]);
        ldA(tb, 3, afB);
        mfma12(afA, bvv[2]);
        ldA(tb, 4, afA);
        mfma12(afB, bvv[3]);
        ldA(tb, 5, afB);
        mfma12(afA, bvv[4]);
        mfma12(afB, bvv[5]);
    }

    // ---- epilogue: C/D 32x32: col = lane&31, row = (reg&3) + 8*(reg>>2) + 4*hl ----
    {
        const float bvls = bias[o];
        #pragma unroll
        for (int rr = 0; rr < 4; ++rr) {
            const int pb = pbase + rr * 32;
            if constexpr (RELU) {
                #pragma unroll
                for (int rg = 0; rg < 4; ++rg)
                    #pragma unroll
                    for (int j = 0; j < 4; ++j) {
                        float v = acc[rr][rg * 4 + j] + bvls;
                        v = v > 0.f ? v : 0.f;
                        const int p = pb + j + 8 * rg + 4 * hl;
                        const int vv = (p >> 5) & 31, ww = p & 31, tu = p >> 10;
                        out_bf[(size_t)nb * 65536 * COUT +
                               (size_t)(tu * 32 + vv) * (32 * COUT) +
                               (o >> 3) * 256 + ww * 8 + (o & 7)] = (__bf16)v;
                    }
            } else {
                #pragma unroll
                for (int rg = 0; rg < 4; ++rg) {
                    f32x4 sv;
                    #pragma unroll
                    for (int j = 0; j < 4; ++j)
                        sv[j] = acc[rr][rg * 4 + j] + bvls;
                    const int p = pb + 8 * rg + 4 * hl;
                    *(f32x4*)(out_f + ((size_t)nb * COUT + o) * 65536 + p) = sv;
                }
            }
        }
    }
}

extern "C" void kernel_launch(void* const* d_in, const int* in_sizes, int n_in,
                              void* d_out, int out_size, void* d_ws, size_t ws_size,
                              hipStream_t stream) {
    const float* x  = (const float*)d_in[0];
    const float* w1 = (const float*)d_in[1];
    const float* b1 = (const float*)d_in[2];
    const float* w2 = (const float*)d_in[3];
    const float* b2 = (const float*)d_in[4];
    float* out = (float*)d_out;

    char* ws = (char*)d_ws;
    __bf16* x_t = (__bf16*)ws;                               // 16,777,216 B
    __bf16* h_t = (__bf16*)(ws + 16777216);                  // 33,554,432 B
    __bf16* w1t = (__bf16*)(ws + 50331648);                  //  1,327,104 B
    __bf16* w2t = (__bf16*)(ws + 51658752);                  //  1,327,104 B
    __bf16* zpg = (__bf16*)(ws + 52985856);                  //      4,096 B

    cvt_x<<<dim3(1024, 2), 256, 0, stream>>>(x, x_t, zpg);
    cvt_w<64><<<81, 256, 0, stream>>>(w1, w1t);
    cvt_w<128><<<81, 256, 0, stream>>>(w2, w2t);

    // conv1: 128-thr blocks, M=128 N=64, COUT split 2 -> grid 2048
    conv4d_mfma<64, 128, 2, true><<<2048, 128, 0, stream>>>(x_t, w1t, b1, h_t,
                                                            nullptr, zpg);
    // conv2: 128-thr blocks, M=128 N=64, grid 1024 (4 blocks/CU)
    conv4d_mfma<128, 64, 1, false><<<1024, 128, 0, stream>>>(h_t, w2t, b2,
                                                             nullptr, out, zpg);
}